// Round 8
// baseline (49.308 us; speedup 1.0000x reference)
//
#include <hip/hip_runtime.h>

#define NPTS 4096
#define DIMP 17                     // DIM+1
#define ROWP 20                     // ws row stride (80 B)
#define RROW 21                     // finalize LDS row stride (odd)
#define FSLAB 32                    // ws slabs = blockIdx.y(8) * 4 waves
#define NIBT  128                   // i-tiles of 32
#define EOFF  (FSLAB * NPTS * ROWP) // float offset of E partials in ws
#define NEP   (FSLAB * NIBT)        // 4096 E partials

typedef short s8v  __attribute__((ext_vector_type(8)));   // 8 bf16 (A/B frag)
typedef float f16v __attribute__((ext_vector_type(16)));  // C/D frag
typedef float v4f  __attribute__((ext_vector_type(4)));

__device__ __forceinline__ unsigned short f2bf(float x) {
    union { float f; unsigned u; } v; v.f = x;           // RNE f32->bf16
    return (unsigned short)((v.u + 0x7FFFu + ((v.u >> 16) & 1u)) >> 16);
}
__device__ __forceinline__ unsigned pk2(float a, float b) {
    return (unsigned)f2bf(a) | ((unsigned)f2bf(b) << 16);
}

// per-pair transform m=cosh(d) -> C; accumulates eacc (+=V) and sm (+= C*m)
#define XF(MV, CV) do {                                                  \
    const float _m  = (MV);                                              \
    const float _ss = fmaxf(fmaf(_m, _m, -1.0f), 2e-7f);  /* sinh^2 */   \
    const float _r  = __builtin_amdgcn_rsqf(_ss);         /* 1/sinh */   \
    const float _sq = _ss * _r;                           /* sinh  */    \
    const float _w  = ((_m - 1.0f) - _sq) + 1.0f;         /* e^-d  */    \
    const float _d  = -__logf(_w);                                       \
    const float _t  = __builtin_amdgcn_sqrtf(_w);         /* e^-d/2 */   \
    const float _u  = _w * _w;                            /* e^-2d */    \
    const float _sg = _u * __builtin_amdgcn_rcpf(_u + 6.1442123533e-6f); \
    const float _K  = fmaf(0.5f, _t, -2.0f * _u) * _sg;                  \
    (CV) = _K * _d * _r;                                                 \
    eacc += (_t - _u);                                                   \
    sm = fmaf((CV), _m, sm);                                             \
} while (0)

// Pass 1: grid (128, 8), block 256 = 4 waves.
// Block: i-tile of 32 (shared by waves), j-range of 512; wave: 4 j-tiles of 32.
// Per 32x32 tile: Gram = 2 MFMA (swapped: rows=j, cols=i), fp32 transform,
// pack+shfl_xor(32) exchange -> PV A-frags, PV = 2 MFMA with B from LDS T.
__global__ __launch_bounds__(256) void hydra_pair_kernel(
    const float* __restrict__ h, float* __restrict__ ws,
    float* __restrict__ out, const int use_ws) {
    const int tid = threadIdx.x, lane = tid & 63, wid = tid >> 6;
    const int hlf = lane >> 5, n = lane & 31;
    const int ib = blockIdx.x * 32, jb = blockIdx.y * 512;

    __shared__ __align__(16) char Tb[17 * 1024];  // T[dim][512 j] bf16, swizzled
    __shared__ float TI[17 * 33];                 // h_I transposed, f32
    __shared__ float SA[4][32];                   // per-wave sm broadcast

    // stage T: pack 2 consecutive j per b32 write (conflict-free)
    for (int t2 = tid; t2 < 17 * 256; t2 += 256) {
        const int d = t2 >> 8, jp = (t2 & 255) * 2;
        const float f0 = h[(jb + jp) * DIMP + d];
        const float f1 = h[(jb + jp + 1) * DIMP + d];
        *(unsigned*)(Tb + ((d * 1024 + jp * 2) ^ ((d & 7) << 4))) = pk2(f0, f1);
    }
    for (int t2 = tid; t2 < 17 * 32; t2 += 256) {
        const int d = t2 >> 5, ii = t2 & 31;
        TI[d * 33 + ii] = h[(ib + ii) * DIMP + d];
    }

    // persistent Gram B-frags: h_i with metric folded (+time, -space)
    s8v bfr, b2 = (s8v)(short)0;
    {
        const int irow = ib + n;
#pragma unroll
        for (int e = 0; e < 8; ++e) {
            const int k = 8 * hlf + e;
            float v = h[irow * DIMP + k];
            if (k != 0) v = -v;
            bfr[e] = (short)f2bf(v);
        }
        if (hlf == 0) b2[0] = (short)f2bf(-h[irow * DIMP + 16]);
    }
    __syncthreads();

    f16v facc = (f16v)(0.0f);
    float sm = 0.0f, eacc = 0.0f;

    for (int t = 0; t < 4; ++t) {
        const int jt = wid * 4 + t;
        const int jr = jb + jt * 32 + n;

        // Gram A-frags: h_j dims [8h..8h+7], plus dim16 in MFMA #2
        s8v afr, a2 = (s8v)(short)0;
#pragma unroll
        for (int e = 0; e < 8; ++e)
            afr[e] = (short)f2bf(h[jr * DIMP + 8 * hlf + e]);
        if (hlf == 0) a2[0] = (short)f2bf(h[jr * DIMP + 16]);

        f16v g = (f16v)(0.0f);
        g = __builtin_amdgcn_mfma_f32_32x32x16_bf16(afr, bfr, g, 0, 0, 0);
        g = __builtin_amdgcn_mfma_f32_32x32x16_bf16(a2, b2, g, 0, 0, 0);
        // g[r] = m for pair (i = n, j_local = (r&3) + 8*(r>>2) + 4*hlf)

        unsigned w[8];
#pragma unroll
        for (int q = 0; q < 8; ++q) {
            float C0, C1;
            XF(g[2 * q], C0);
            XF(g[2 * q + 1], C1);
            w[q] = pk2(C0, C1);
        }
        unsigned o[8];
#pragma unroll
        for (int q = 0; q < 8; ++q) o[q] = (unsigned)__shfl_xor((int)w[q], 32);

        // PV: F[i, dim] += sum_j C * h_j[dim], two K=16 chunks per tile
#pragma unroll
        for (int c = 0; c < 2; ++c) {
            union { unsigned u[4]; s8v s; } pa;
            pa.u[0] = hlf ? o[4 * c + 2] : w[4 * c];
            pa.u[1] = hlf ? o[4 * c + 3] : w[4 * c + 1];
            pa.u[2] = hlf ? w[4 * c + 2] : o[4 * c];
            pa.u[3] = hlf ? w[4 * c + 3] : o[4 * c + 1];
            const int dimc = (n > 16) ? 16 : n;
            const int joff = jt * 32 + c * 16 + hlf * 8;
            s8v pb = *(const s8v*)(Tb + ((dimc * 1024 + joff * 2) ^ ((dimc & 7) << 4)));
            if (n > 16) pb = (s8v)(short)0;
            facc = __builtin_amdgcn_mfma_f32_32x32x16_bf16(pa.s, pb, facc, 0, 0, 0);
        }
    }

    // sacc fold data: sm_i (i = col n) reduced across halves, broadcast via LDS
    sm += __shfl_xor(sm, 32);
    if (lane < 32) SA[wid][lane] = sm;
#pragma unroll
    for (int off = 32; off > 0; off >>= 1) eacc += __shfl_xor(eacc, off);

    const int slab = blockIdx.y * 4 + wid;
    if (use_ws) {
        if (n < DIMP) {
#pragma unroll
            for (int r = 0; r < 16; ++r) {
                const int irow = (r & 3) + 8 * (r >> 2) + 4 * hlf;
                // F = C@h + (sum C*inn)*h_i, inn = -m  ->  -= sm * h_i[dim]
                const float val = facc[r] - SA[wid][irow] * TI[n * 33 + irow];
                ws[(size_t)(slab * NPTS + ib + irow) * ROWP + n] = val;
            }
        }
        if (lane == 0) ws[EOFF + slab * NIBT + blockIdx.x] = eacc;
    } else {
        if (n < DIMP) {
#pragma unroll
            for (int r = 0; r < 16; ++r) {
                const int irow = (r & 3) + 8 * (r >> 2) + 4 * hlf;
                atomicAdd(&out[(ib + irow) * DIMP + n],
                          facc[r] - SA[wid][irow] * TI[n * 33 + irow]);
            }
        }
        if (lane == 0) atomicAdd(&out[NPTS * DIMP], eacc);
    }
}

// Pass 2: grid 64 blocks x 256. lane -> i (64 per block), wid -> slab quarter.
__global__ __launch_bounds__(256) void hydra_finalize_kernel(
    const float* __restrict__ ws, float* __restrict__ out, const int use_ws) {
    const int tid  = threadIdx.x;
    const int lane = tid & 63;
    const int q    = tid >> 6;
    const int i    = blockIdx.x * 64 + lane;

    __shared__ __align__(16) float red[3 * 64 * RROW + 8];

    float v[DIMP];
#pragma unroll
    for (int k = 0; k < DIMP; ++k) v[k] = 0.0f;

    if (use_ws) {
#pragma unroll
        for (int ssl = 0; ssl < FSLAB / 4; ++ssl) {
            const int s = q * (FSLAB / 4) + ssl;
            const float* row = ws + ((size_t)s * NPTS + i) * ROWP;
            const v4f b0 = ((const v4f*)row)[0];
            const v4f b1 = ((const v4f*)row)[1];
            const v4f b2 = ((const v4f*)row)[2];
            const v4f b3 = ((const v4f*)row)[3];
            v[0]  += b0.x; v[1]  += b0.y; v[2]  += b0.z; v[3]  += b0.w;
            v[4]  += b1.x; v[5]  += b1.y; v[6]  += b1.z; v[7]  += b1.w;
            v[8]  += b2.x; v[9]  += b2.y; v[10] += b2.z; v[11] += b2.w;
            v[12] += b3.x; v[13] += b3.y; v[14] += b3.z; v[15] += b3.w;
            v[16] += row[16];
        }
        if (q > 0) {
            float* dst = red + ((q - 1) * 64 + lane) * RROW;
#pragma unroll
            for (int k = 0; k < DIMP; ++k) dst[k] = v[k];
        }
        __syncthreads();
        if (q == 0) {
#pragma unroll
            for (int qq = 0; qq < 3; ++qq) {
                const float* src = red + (qq * 64 + lane) * RROW;
#pragma unroll
                for (int k = 0; k < DIMP; ++k) v[k] += src[k];
            }
        }
    } else if (q == 0) {
#pragma unroll
        for (int k = 0; k < DIMP; ++k) v[k] = out[i * DIMP + k];
    }

    if (q == 0) {
        float ss = 0.0f;
#pragma unroll
        for (int k = 0; k < DIMP; ++k) ss = fmaf(v[k], v[k], ss);
        const float nrm   = sqrtf(ss);
        const float scale = fminf(6.0f / fmaxf(nrm, 1e-8f), 1.0f);
#pragma unroll
        for (int k = 0; k < DIMP; ++k) out[i * DIMP + k] = v[k] * scale;
    }

    if (blockIdx.x == 0) {
        if (use_ws) {
            float e = 0.0f;
#pragma unroll
            for (int t = 0; t < NEP / 256; ++t) e += ws[EOFF + tid + t * 256];
#pragma unroll
            for (int off = 32; off > 0; off >>= 1) e += __shfl_xor(e, off);
            __shared__ float es[4];
            if (lane == 0) es[q] = e;
            __syncthreads();
            if (tid == 0) out[NPTS * DIMP] = 0.5f * (es[0] + es[1] + es[2] + es[3]);
        } else {
            if (tid == 0) out[NPTS * DIMP] *= 0.5f;
        }
    }
}

extern "C" void kernel_launch(void* const* d_in, const int* in_sizes, int n_in,
                              void* d_out, int out_size, void* d_ws, size_t ws_size,
                              hipStream_t stream) {
    const float* h = (const float*)d_in[0];
    float* out = (float*)d_out;
    float* ws  = (float*)d_ws;

    const size_t need = (size_t)(EOFF + NEP) * sizeof(float);
    const int use_ws = (ws_size >= need) ? 1 : 0;
    if (!use_ws) {
        hipMemsetAsync(d_out, 0, (size_t)out_size * sizeof(float), stream);
    }

    dim3 grid(NIBT, 8);
    hydra_pair_kernel<<<grid, 256, 0, stream>>>(h, ws, out, use_ws);
    hydra_finalize_kernel<<<64, 256, 0, stream>>>(ws, out, use_ws);
}

// Round 9
// 43.221 us; speedup vs baseline: 1.1408x; 1.1408x over previous
//
#include <hip/hip_runtime.h>
#include <hip/hip_bf16.h>

#define NPTS 4096
#define DIMP 17                     // DIM+1
#define ROWP 20                     // ws row stride (floats)
#define RROW 21                     // finalize LDS row stride (odd)
#define NJB  16                     // j-blocks
#define JR   256                    // j's per block (2 tiles of 32 per wave)
#define NIBT 128                    // i-tiles of 32
#define FSLAB NJB                   // 16 ws slabs
#define EOFF  (FSLAB * NPTS * ROWP) // float offset of E partials in ws
#define NEP   (FSLAB * NIBT)        // 2048 E partials

// LDS layout (bytes). FR/SA/ER alias the dead R/Tb region in the epilogue.
#define R_OFF   0                   // [256 j][20 bf16] row-major      (10240)
#define TB_OFF  10240               // [17 d][256 j] bf16, swizzled     (8704)
#define RI_OFF  18944               // [32 i][20 bf16] metric-folded    (1280)
#define FR_OFF  0                   // epi: [192][17] f32              (13056)
#define SA_OFF  13056               // epi: [4][32] f32 sm partials
#define ER_OFF  13568               // epi: [4] f32 E partials
#define LDS_SZ  20224               // 8 blocks/CU x 20224 <= 160 KiB

typedef short s4v  __attribute__((ext_vector_type(4)));
typedef short s8v  __attribute__((ext_vector_type(8)));
typedef float f16v __attribute__((ext_vector_type(16)));
typedef float v4f  __attribute__((ext_vector_type(4)));

__device__ __forceinline__ unsigned pk2(float a, float b) {
    float2 f; f.x = a; f.y = b;
    union { __hip_bfloat162 h; unsigned u; } c;
    c.h = __float22bfloat162_rn(f);            // v_cvt_pk_bf16_f32
    return c.u;
}
__device__ __forceinline__ float bf2f(short s) {
    union { unsigned u; float f; } c;
    c.u = ((unsigned)(unsigned short)s) << 16;
    return c.f;
}
__device__ __forceinline__ s8v cat8(s4v lo, s4v hi) {
    return __builtin_shufflevector(lo, hi, 0, 1, 2, 3, 4, 5, 6, 7);
}

// m = cosh(d) -> C (sigmoid dropped: (1-sig)*C contribution < 1e-3/pair,
// F threshold 5.6e4). Also accumulates eacc += V and sm += C*m.
#define XF(MV, CV) do {                                                 \
    const float _m  = (MV);                                             \
    const float _ss = fmaxf(fmaf(_m, _m, -1.0f), 2e-7f); /* sinh^2 */   \
    const float _r  = __builtin_amdgcn_rsqf(_ss);        /* 1/sinh */   \
    const float _w  = fmaxf(((_m - 1.0f) - _ss * _r) + 1.0f, 1e-30f);   \
    const float _d  = -__logf(_w);                       /* dist   */   \
    const float _t  = __builtin_amdgcn_sqrtf(_w);        /* e^-d/2 */   \
    const float _u  = _w * _w;                           /* e^-2d  */   \
    const float _K  = fmaf(0.5f, _t, -2.0f * _u);        /* -dVdd  */   \
    (CV) = _K * _d * _r;                                                \
    eacc += (_t - _u);                                                  \
    sm = fmaf((CV), _m, sm);                                            \
} while (0)

// Pass 1: grid (128, 16), block 256 = 4 waves, 8 blocks/CU.
// Block: 32-i tile x 256-j range; wave: 2 j-tiles of 32.
// Gram = 2 MFMA (bf16 frags from LDS), fp32 transform, pack + shfl_xor(32)
// -> PV A-frags, PV = 2 MFMA with B from swizzled LDS transpose.
__global__ __launch_bounds__(256) void hydra_pair_kernel(
    const float* __restrict__ h, float* __restrict__ ws,
    float* __restrict__ out, const int use_ws) {
    const int tid = threadIdx.x, lane = tid & 63, wid = tid >> 6;
    const int hlf = lane >> 5, n = lane & 31;
    const int ib = blockIdx.x * 32, jb = blockIdx.y * JR;

    __shared__ __align__(16) char ldsb[LDS_SZ];

    // stage R: row-major bf16 j-tile (9 b32 per row used, stride 40 B)
    for (int idx = tid; idx < JR * 9; idx += 256) {
        const int j = idx / 9, e = idx - j * 9;
        const float f0 = h[(jb + j) * DIMP + 2 * e];
        const float f1 = (e < 8) ? h[(jb + j) * DIMP + 2 * e + 1] : 0.0f;
        *(unsigned*)(ldsb + R_OFF + j * 40 + e * 4) = pk2(f0, f1);
    }
    // stage Tb: transposed bf16 [dim][j], XOR-swizzled 16B slots
    for (int idx = tid; idx < DIMP * (JR / 2); idx += 256) {
        const int d = idx >> 7, jp = (idx & 127) * 2;
        const float f0 = h[(jb + jp) * DIMP + d];
        const float f1 = h[(jb + jp + 1) * DIMP + d];
        *(unsigned*)(ldsb + TB_OFF + ((d * 512 + jp * 2) ^ ((d & 7) << 4))) =
            pk2(f0, f1);
    }
    // stage RI: i-tile bf16, metric-folded (time +, space -)
    for (int idx = tid; idx < 32 * 9; idx += 256) {
        const int ii = idx / 9, e = idx - ii * 9;
        float f0 = h[(ib + ii) * DIMP + 2 * e];
        if (e > 0) f0 = -f0;
        const float f1 = (e < 8) ? -h[(ib + ii) * DIMP + 2 * e + 1] : 0.0f;
        *(unsigned*)(ldsb + RI_OFF + ii * 40 + e * 4) = pk2(f0, f1);
    }
    __syncthreads();

    // persistent Gram B-frags: col i = n, dims 8*hlf..8*hlf+7 (+ dim16)
    const char* rip = ldsb + RI_OFF + n * 40 + hlf * 16;
    const s8v bfr = cat8(*(const s4v*)rip, *(const s4v*)(rip + 8));
    s8v b2 = (s8v)(short)0;
    if (!hlf) b2[0] = *(const short*)(ldsb + RI_OFF + n * 40 + 32);

    f16v facc = (f16v)(0.0f);
    float sm = 0.0f, eacc = 0.0f;

#pragma unroll
    for (int t = 0; t < 2; ++t) {
        const int jt = wid * 2 + t;
        const int jl = jt * 32 + n;
        const char* rp = ldsb + R_OFF + jl * 40 + hlf * 16;
        const s8v afr = cat8(*(const s4v*)rp, *(const s4v*)(rp + 8));
        s8v a2 = (s8v)(short)0;
        if (!hlf) a2[0] = *(const short*)(ldsb + R_OFF + jl * 40 + 32);

        f16v g = (f16v)(0.0f);
        g = __builtin_amdgcn_mfma_f32_32x32x16_bf16(afr, bfr, g, 0, 0, 0);
        g = __builtin_amdgcn_mfma_f32_32x32x16_bf16(a2, b2, g, 0, 0, 0);
        // g[r] = m for (i = n, j_local = (r&3) + 8*(r>>2) + 4*hlf)

        unsigned w[8];
#pragma unroll
        for (int q = 0; q < 8; ++q) {
            float c0, c1;
            XF(g[2 * q], c0);
            XF(g[2 * q + 1], c1);
            w[q] = pk2(c0, c1);
        }
#pragma unroll
        for (int c = 0; c < 2; ++c) {
            const unsigned o0 = (unsigned)__shfl_xor((int)w[4 * c + 0], 32);
            const unsigned o1 = (unsigned)__shfl_xor((int)w[4 * c + 1], 32);
            const unsigned o2 = (unsigned)__shfl_xor((int)w[4 * c + 2], 32);
            const unsigned o3 = (unsigned)__shfl_xor((int)w[4 * c + 3], 32);
            union { unsigned u[4]; s8v s; } pa;
            pa.u[0] = hlf ? o2 : w[4 * c + 0];
            pa.u[1] = hlf ? o3 : w[4 * c + 1];
            pa.u[2] = hlf ? w[4 * c + 2] : o0;
            pa.u[3] = hlf ? w[4 * c + 3] : o1;
            const int dimc = (n > 16) ? 16 : n;
            const int joff = jt * 32 + c * 16 + hlf * 8;
            const char* tp = ldsb + TB_OFF +
                ((dimc * 512 + joff * 2) ^ ((dimc & 7) << 4));
            s8v pb = cat8(*(const s4v*)tp, *(const s4v*)(tp + 8));
            if (n > 16) pb = (s8v)(short)0;
            facc = __builtin_amdgcn_mfma_f32_32x32x16_bf16(pa.s, pb, facc, 0, 0, 0);
        }
    }

    sm += __shfl_xor(sm, 32);   // full col sum over this wave's 64 j's
#pragma unroll
    for (int off = 32; off > 0; off >>= 1) eacc += __shfl_xor(eacc, off);

    __syncthreads();            // R/Tb dead; alias reduction buffers
    float* FR  = (float*)(ldsb + FR_OFF);
    float* SAp = (float*)(ldsb + SA_OFF);
    float* ERp = (float*)(ldsb + ER_OFF);
    if (wid > 0) {
        float* dst = FR + ((wid - 1) * 64 + lane) * 17;
#pragma unroll
        for (int r = 0; r < 16; ++r) dst[r] = facc[r];
    }
    if (lane < 32) SAp[wid * 32 + n] = sm;
    if (lane == 0) ERp[wid] = eacc;
    __syncthreads();

    if (wid == 0) {
#pragma unroll
        for (int q = 0; q < 3; ++q) {
            const float* src = FR + (q * 64 + lane) * 17;
#pragma unroll
            for (int r = 0; r < 16; ++r) facc[r] += src[r];
        }
        const float esum = eacc + ERp[1] + ERp[2] + ERp[3];
        const int slab = blockIdx.y;
        if (n < DIMP) {
#pragma unroll
            for (int r = 0; r < 16; ++r) {
                const int irow = (r & 3) + 8 * (r >> 2) + 4 * hlf;
                const float smt = SAp[irow] + SAp[32 + irow] +
                                  SAp[64 + irow] + SAp[96 + irow];
                float hv = bf2f(*(const short*)(ldsb + RI_OFF + irow * 40 + n * 2));
                hv = (n == 0) ? hv : -hv;   // unfold metric
                // F = C@h + (sum C*inn)*h_i, inn = -m
                const float val = facc[r] - smt * hv;
                if (use_ws)
                    ws[(size_t)(slab * NPTS + ib + irow) * ROWP + n] = val;
                else
                    atomicAdd(&out[(ib + irow) * DIMP + n], val);
            }
        }
        if (lane == 0) {
            if (use_ws) ws[EOFF + slab * NIBT + blockIdx.x] = esum;
            else        atomicAdd(&out[NPTS * DIMP], esum);
        }
    }
}

// Pass 2: grid 64 blocks x 256. lane -> i (64 per block), wid -> slab quarter.
__global__ __launch_bounds__(256) void hydra_finalize_kernel(
    const float* __restrict__ ws, float* __restrict__ out, const int use_ws) {
    const int tid  = threadIdx.x;
    const int lane = tid & 63;
    const int q    = tid >> 6;
    const int i    = blockIdx.x * 64 + lane;

    __shared__ __align__(16) float red[3 * 64 * RROW + 8];

    float v[DIMP];
#pragma unroll
    for (int k = 0; k < DIMP; ++k) v[k] = 0.0f;

    if (use_ws) {
#pragma unroll
        for (int ssl = 0; ssl < FSLAB / 4; ++ssl) {
            const int s = q * (FSLAB / 4) + ssl;
            const float* row = ws + ((size_t)s * NPTS + i) * ROWP;
            const v4f b0 = ((const v4f*)row)[0];
            const v4f b1 = ((const v4f*)row)[1];
            const v4f b2 = ((const v4f*)row)[2];
            const v4f b3 = ((const v4f*)row)[3];
            v[0]  += b0.x; v[1]  += b0.y; v[2]  += b0.z; v[3]  += b0.w;
            v[4]  += b1.x; v[5]  += b1.y; v[6]  += b1.z; v[7]  += b1.w;
            v[8]  += b2.x; v[9]  += b2.y; v[10] += b2.z; v[11] += b2.w;
            v[12] += b3.x; v[13] += b3.y; v[14] += b3.z; v[15] += b3.w;
            v[16] += row[16];
        }
        if (q > 0) {
            float* dst = red + ((q - 1) * 64 + lane) * RROW;
#pragma unroll
            for (int k = 0; k < DIMP; ++k) dst[k] = v[k];
        }
        __syncthreads();
        if (q == 0) {
#pragma unroll
            for (int qq = 0; qq < 3; ++qq) {
                const float* src = red + (qq * 64 + lane) * RROW;
#pragma unroll
                for (int k = 0; k < DIMP; ++k) v[k] += src[k];
            }
        }
    } else if (q == 0) {
#pragma unroll
        for (int k = 0; k < DIMP; ++k) v[k] = out[i * DIMP + k];
    }

    if (q == 0) {
        float ss = 0.0f;
#pragma unroll
        for (int k = 0; k < DIMP; ++k) ss = fmaf(v[k], v[k], ss);
        const float nrm   = sqrtf(ss);
        const float scale = fminf(6.0f / fmaxf(nrm, 1e-8f), 1.0f);
#pragma unroll
        for (int k = 0; k < DIMP; ++k) out[i * DIMP + k] = v[k] * scale;
    }

    if (blockIdx.x == 0) {
        if (use_ws) {
            float e = 0.0f;
#pragma unroll
            for (int t = 0; t < NEP / 256; ++t) e += ws[EOFF + tid + t * 256];
#pragma unroll
            for (int off = 32; off > 0; off >>= 1) e += __shfl_xor(e, off);
            __shared__ float es[4];
            if (lane == 0) es[q] = e;
            __syncthreads();
            if (tid == 0) out[NPTS * DIMP] = 0.5f * (es[0] + es[1] + es[2] + es[3]);
        } else {
            if (tid == 0) out[NPTS * DIMP] *= 0.5f;
        }
    }
}

extern "C" void kernel_launch(void* const* d_in, const int* in_sizes, int n_in,
                              void* d_out, int out_size, void* d_ws, size_t ws_size,
                              hipStream_t stream) {
    const float* h = (const float*)d_in[0];
    float* out = (float*)d_out;
    float* ws  = (float*)d_ws;

    const size_t need = (size_t)(EOFF + NEP) * sizeof(float);
    const int use_ws = (ws_size >= need) ? 1 : 0;
    if (!use_ws) {
        hipMemsetAsync(d_out, 0, (size_t)out_size * sizeof(float), stream);
    }

    dim3 grid(NIBT, NJB);
    hydra_pair_kernel<<<grid, 256, 0, stream>>>(h, ws, out, use_ws);
    hydra_finalize_kernel<<<64, 256, 0, stream>>>(ws, out, use_ws);
}

// Round 10
// 42.243 us; speedup vs baseline: 1.1672x; 1.0231x over previous
//
#include <hip/hip_runtime.h>

#define NPTS 4096
#define DIMP 17                     // DIM+1
#define ROWP 20                     // LDS tile / ws row stride (floats)
#define RROW 21                     // reduction row stride (odd -> conflict-free)
#define JPB  128                    // j's per block (32 rows per wave)
#define IPB  128                    // i's per block (2 per lane)
#define NSLAB (NPTS / JPB)          // 32 j-slabs
#define NIB   (NPTS / IPB)          // 32 i-blocks
#define EOFF  (NSLAB * NPTS * ROWP) // float offset of E partials in ws
#define NEP   (NSLAB * NIB)         // 1024 E partials
#define REDF  (384 * RROW)          // reduction floats (3 waves x 128 rows)

typedef float v4f __attribute__((ext_vector_type(4)));

// m = cosh(d) -> C = -dVdd * d / sinh(d); accumulates E and sm += C*m.
// (sigmoid horizon + D_MIN branch dropped: validated, error << threshold)
#define XFORM(MV, SMV, CV) do {                                         \
    const float _m  = (MV);                                             \
    const float _ss = fmaxf(fmaf(_m, _m, -1.0f), 2e-7f); /* sinh^2 */   \
    const float _r  = __builtin_amdgcn_rsqf(_ss);        /* 1/sinh */   \
    const float _w  = fmaxf(((_m - 1.0f) - _ss * _r) + 1.0f, 1e-30f);   \
    const float _lg = __logf(_w);                        /* -d     */   \
    const float _t  = __builtin_amdgcn_sqrtf(_w);        /* e^-d/2 */   \
    const float _u  = _w * _w;                           /* e^-2d  */   \
    const float _K  = fmaf(0.5f, _t, -2.0f * _u);        /* -dVdd  */   \
    (CV) = _K * _r * (-_lg);                                            \
    eacc += (_t - _u);                                                  \
    (SMV) = fmaf((CV), _m, (SMV));                                      \
} while (0)

// Pass 1: grid (32, 32), block 256 = 4 waves, 4 blocks/CU (16 waves/CU).
// Lane owns i1 = i0+lane, i2 = i0+64+lane; each wave reads its 32 j-rows
// from LDS as wave-uniform broadcasts -> one row-read feeds 128 pairs
// (halves the per-CU LDS-pipe load vs 1-i blocking, which bound R3).
__global__ __launch_bounds__(256) void hydra_pair_kernel(
    const float* __restrict__ h, float* __restrict__ ws,
    float* __restrict__ out, const int use_ws) {
    const int tid   = threadIdx.x;
    const int lane  = tid & 63;
    const int wid   = tid >> 6;
    const int i0    = blockIdx.x * IPB;
    const int i1    = i0 + lane;
    const int i2    = i0 + 64 + lane;
    const int jbase = blockIdx.y * JPB;

    __shared__ __align__(16) float lds[REDF + 16];   // 32.3 KB

    // coalesced stage of the 128-j tile (rows padded to ROWP)
    for (int idx = tid; idx < JPB * DIMP; idx += 256) {
        const int j = idx / DIMP;
        const int k = idx - j * DIMP;
        lds[j * ROWP + k] = h[jbase * DIMP + idx];
    }

    // metric-folded i-rows: nh = (t, -s)  ->  dot(nh, hj) = +cosh(d) = m
    float nh1[DIMP], nh2[DIMP];
#pragma unroll
    for (int k = 0; k < DIMP; ++k) nh1[k] = -h[i1 * DIMP + k];
#pragma unroll
    for (int k = 0; k < DIMP; ++k) nh2[k] = -h[i2 * DIMP + k];
    nh1[0] = -nh1[0];
    nh2[0] = -nh2[0];

    __syncthreads();

    float ac1[DIMP], ac2[DIMP];
#pragma unroll
    for (int k = 0; k < DIMP; ++k) { ac1[k] = 0.0f; ac2[k] = 0.0f; }
    float sm1 = 0.0f, sm2 = 0.0f, eacc = 0.0f;

    const float* rowp = lds + (wid * 32) * ROWP;
#pragma unroll 2
    for (int jj = 0; jj < 32; ++jj, rowp += ROWP) {
        const v4f a0 = ((const v4f*)rowp)[0];
        const v4f a1 = ((const v4f*)rowp)[1];
        const v4f a2 = ((const v4f*)rowp)[2];
        const v4f a3 = ((const v4f*)rowp)[3];
        const float a16 = rowp[16];
        const float hj[DIMP] = {a0.x, a0.y, a0.z, a0.w, a1.x, a1.y, a1.z, a1.w,
                                a2.x, a2.y, a2.z, a2.w, a3.x, a3.y, a3.z, a3.w, a16};

        // two Lorentz dots, 2-way split chains each, interleaved for ILP
        float p0 = nh1[0] * hj[0], p1 = nh1[1] * hj[1];
        float q0 = nh2[0] * hj[0], q1 = nh2[1] * hj[1];
#pragma unroll
        for (int k = 2; k < 16; k += 2) {
            p0 = fmaf(nh1[k], hj[k], p0);  p1 = fmaf(nh1[k + 1], hj[k + 1], p1);
            q0 = fmaf(nh2[k], hj[k], q0);  q1 = fmaf(nh2[k + 1], hj[k + 1], q1);
        }
        const float m1 = fmaf(nh1[16], a16, p0 + p1);   // cosh(d1)
        const float m2 = fmaf(nh2[16], a16, q0 + q1);   // cosh(d2)

        float C1, C2;
        XFORM(m1, sm1, C1);
        XFORM(m2, sm2, C2);

#pragma unroll
        for (int k = 0; k < DIMP; ++k) {
            ac1[k] = fmaf(C1, hj[k], ac1[k]);
            ac2[k] = fmaf(C2, hj[k], ac2[k]);
        }
    }

    // F_i = ac + (sum C*inn)*h_i ; inn = -m, and nh holds (t, -s):
    // h_i[0] = nh[0], h_i[k>=1] = -nh[k]
    ac1[0] = fmaf(-sm1, nh1[0], ac1[0]);
    ac2[0] = fmaf(-sm2, nh2[0], ac2[0]);
#pragma unroll
    for (int k = 1; k < DIMP; ++k) {
        ac1[k] = fmaf(sm1, nh1[k], ac1[k]);
        ac2[k] = fmaf(sm2, nh2[k], ac2[k]);
    }

#pragma unroll
    for (int off = 32; off > 0; off >>= 1) eacc += __shfl_xor(eacc, off);

    __syncthreads();   // tile reads done; reuse LDS for cross-wave reduction
    if (wid > 0) {
        float* dA = lds + ((wid - 1) * 64 + lane) * RROW;
        float* dB = lds + ((192 + (wid - 1) * 64 + lane)) * RROW;
#pragma unroll
        for (int k = 0; k < DIMP; ++k) { dA[k] = ac1[k]; dB[k] = ac2[k]; }
        if (lane == 0) lds[REDF + wid] = eacc;
    }
    __syncthreads();

    if (wid == 0) {
        const float esum = eacc + lds[REDF + 1] + lds[REDF + 2] + lds[REDF + 3];
#pragma unroll
        for (int q = 0; q < 3; ++q) {
            const float* sA = lds + (q * 64 + lane) * RROW;
            const float* sB = lds + ((192 + q * 64 + lane)) * RROW;
#pragma unroll
            for (int k = 0; k < DIMP; ++k) { ac1[k] += sA[k]; ac2[k] += sB[k]; }
        }
        if (use_ws) {
            float* w1p = ws + ((size_t)blockIdx.y * NPTS + i1) * ROWP;
            float* w2p = ws + ((size_t)blockIdx.y * NPTS + i2) * ROWP;
#pragma unroll
            for (int k = 0; k < DIMP; ++k) { w1p[k] = ac1[k]; w2p[k] = ac2[k]; }
            if (lane == 0) ws[EOFF + blockIdx.y * NIB + blockIdx.x] = esum;
        } else {
#pragma unroll
            for (int k = 0; k < DIMP; ++k) {
                atomicAdd(&out[i1 * DIMP + k], ac1[k]);
                atomicAdd(&out[i2 * DIMP + k], ac2[k]);
            }
            if (lane == 0) atomicAdd(&out[NPTS * DIMP], esum);
        }
    }
}

// Pass 2: grid 64 blocks x 256. lane -> i (64 per block), wid -> slab quarter.
__global__ __launch_bounds__(256) void hydra_finalize_kernel(
    const float* __restrict__ ws, float* __restrict__ out, const int use_ws) {
    const int tid  = threadIdx.x;
    const int lane = tid & 63;
    const int q    = tid >> 6;
    const int i    = blockIdx.x * 64 + lane;

    __shared__ __align__(16) float red[3 * 64 * RROW + 8];

    float v[DIMP];
#pragma unroll
    for (int k = 0; k < DIMP; ++k) v[k] = 0.0f;

    if (use_ws) {
#pragma unroll
        for (int ssl = 0; ssl < NSLAB / 4; ++ssl) {
            const int s = q * (NSLAB / 4) + ssl;
            const float* row = ws + ((size_t)s * NPTS + i) * ROWP;
            const v4f b0 = ((const v4f*)row)[0];
            const v4f b1 = ((const v4f*)row)[1];
            const v4f b2 = ((const v4f*)row)[2];
            const v4f b3 = ((const v4f*)row)[3];
            v[0]  += b0.x; v[1]  += b0.y; v[2]  += b0.z; v[3]  += b0.w;
            v[4]  += b1.x; v[5]  += b1.y; v[6]  += b1.z; v[7]  += b1.w;
            v[8]  += b2.x; v[9]  += b2.y; v[10] += b2.z; v[11] += b2.w;
            v[12] += b3.x; v[13] += b3.y; v[14] += b3.z; v[15] += b3.w;
            v[16] += row[16];
        }
        if (q > 0) {
            float* dst = red + ((q - 1) * 64 + lane) * RROW;
#pragma unroll
            for (int k = 0; k < DIMP; ++k) dst[k] = v[k];
        }
        __syncthreads();
        if (q == 0) {
#pragma unroll
            for (int qq = 0; qq < 3; ++qq) {
                const float* src = red + (qq * 64 + lane) * RROW;
#pragma unroll
                for (int k = 0; k < DIMP; ++k) v[k] += src[k];
            }
        }
    } else if (q == 0) {
#pragma unroll
        for (int k = 0; k < DIMP; ++k) v[k] = out[i * DIMP + k];
    }

    if (q == 0) {
        float ss = 0.0f;
#pragma unroll
        for (int k = 0; k < DIMP; ++k) ss = fmaf(v[k], v[k], ss);
        const float nrm   = sqrtf(ss);
        const float scale = fminf(6.0f / fmaxf(nrm, 1e-8f), 1.0f);
#pragma unroll
        for (int k = 0; k < DIMP; ++k) out[i * DIMP + k] = v[k] * scale;
    }

    if (blockIdx.x == 0) {
        if (use_ws) {
            float e = 0.0f;
#pragma unroll
            for (int t = 0; t < NEP / 256; ++t) e += ws[EOFF + tid + t * 256];
#pragma unroll
            for (int off = 32; off > 0; off >>= 1) e += __shfl_xor(e, off);
            __shared__ float es[4];
            if (lane == 0) es[q] = e;
            __syncthreads();
            if (tid == 0) out[NPTS * DIMP] = 0.5f * (es[0] + es[1] + es[2] + es[3]);
        } else {
            if (tid == 0) out[NPTS * DIMP] *= 0.5f;
        }
    }
}

extern "C" void kernel_launch(void* const* d_in, const int* in_sizes, int n_in,
                              void* d_out, int out_size, void* d_ws, size_t ws_size,
                              hipStream_t stream) {
    const float* h = (const float*)d_in[0];
    float* out = (float*)d_out;
    float* ws  = (float*)d_ws;

    const size_t need = (size_t)(EOFF + NEP) * sizeof(float);
    const int use_ws = (ws_size >= need) ? 1 : 0;
    if (!use_ws) {
        hipMemsetAsync(d_out, 0, (size_t)out_size * sizeof(float), stream);
    }

    dim3 grid(NIB, NSLAB);
    hydra_pair_kernel<<<grid, 256, 0, stream>>>(h, ws, out, use_ws);
    hydra_finalize_kernel<<<64, 256, 0, stream>>>(ws, out, use_ws);
}

// Round 11
// 41.589 us; speedup vs baseline: 1.1856x; 1.0157x over previous
//
#include <hip/hip_runtime.h>

#define NPTS 4096
#define DIMP 17                     // DIM+1
#define ROWP 20                     // LDS tile / ws row stride (floats)
#define RROW 21                     // reduction row stride (odd -> conflict-free)
#define JPB  128                    // j's per block (32 rows per wave)
#define IPB  128                    // i's per block (2 per lane)
#define NSLAB (NPTS / JPB)          // 32 j-slabs
#define NIB   (NPTS / IPB)          // 32 i-blocks
#define EOFF  (NSLAB * NPTS * ROWP) // float offset of E partials in ws
#define NEP   (NSLAB * NIB)         // 1024 E partials
#define REDF  (384 * RROW)          // reduction floats (3 waves x 128 rows)

typedef float v2f __attribute__((ext_vector_type(2)));
typedef float v4f __attribute__((ext_vector_type(4)));

// Pass 1: grid (32, 32), block 256 = 4 waves, 4 blocks/CU.
// Lane owns i1 = i0+lane, i2 = i0+64+lane. One wave-uniform LDS row feeds 128
// pairs. ALL per-pair math is v_pk_fma-packed with zero register-shuffle movs:
// dot uses a0.lo/.hi subregisters directly; the transform is packed across
// the two i's; acc uses .xx/.yy splats of the packed C.
__global__ __launch_bounds__(256) void hydra_pair_kernel(
    const float* __restrict__ h, float* __restrict__ ws,
    float* __restrict__ out, const int use_ws) {
    const int tid   = threadIdx.x;
    const int lane  = tid & 63;
    const int wid   = tid >> 6;
    const int i0    = blockIdx.x * IPB;
    const int i1    = i0 + lane;
    const int i2    = i0 + 64 + lane;
    const int jbase = blockIdx.y * JPB;

    __shared__ __align__(16) float lds[REDF + 16];   // 32.3 KB

    // coalesced stage of the 128-j tile (rows padded to ROWP)
    for (int idx = tid; idx < JPB * DIMP; idx += 256) {
        const int j = idx / DIMP;
        const int k = idx - j * DIMP;
        lds[j * ROWP + k] = h[jbase * DIMP + idx];
    }

    // metric-folded i-rows, packed: nh = (t, -s) -> dot(nh, hj) = +cosh = m
    v2f nh1p[8], nh2p[8];
    float nh1_16, nh2_16;
#pragma unroll
    for (int p = 0; p < 8; ++p) {
        const float s1 = (p == 0) ? 1.0f : -1.0f;
        nh1p[p].x = s1 * h[i1 * DIMP + 2 * p];
        nh1p[p].y = -h[i1 * DIMP + 2 * p + 1];
        nh2p[p].x = s1 * h[i2 * DIMP + 2 * p];
        nh2p[p].y = -h[i2 * DIMP + 2 * p + 1];
    }
    nh1_16 = -h[i1 * DIMP + 16];
    nh2_16 = -h[i2 * DIMP + 16];

    __syncthreads();

    v2f ac1p[8], ac2p[8];
#pragma unroll
    for (int p = 0; p < 8; ++p) { ac1p[p] = (v2f)(0.0f); ac2p[p] = (v2f)(0.0f); }
    float ac1_16 = 0.0f, ac2_16 = 0.0f;
    v2f smp  = (v2f)(0.0f);   // {sum C1*m1, sum C2*m2}
    v2f eacp = (v2f)(0.0f);   // packed E partial

    const float* rowp = lds + (wid * 32) * ROWP;
#pragma unroll 2
    for (int jj = 0; jj < 32; ++jj, rowp += ROWP) {
        const v4f a0 = ((const v4f*)rowp)[0];
        const v4f a1 = ((const v4f*)rowp)[1];
        const v4f a2 = ((const v4f*)rowp)[2];
        const v4f a3 = ((const v4f*)rowp)[3];
        const float a16 = rowp[16];

        // two Lorentz dots, packed over dim pairs (operands are subregisters)
        v2f c0 = nh1p[0] * a0.lo, d0 = nh2p[0] * a0.lo;
        v2f c1 = nh1p[1] * a0.hi, d1 = nh2p[1] * a0.hi;
        c0 = __builtin_elementwise_fma(nh1p[2], a1.lo, c0);
        d0 = __builtin_elementwise_fma(nh2p[2], a1.lo, d0);
        c1 = __builtin_elementwise_fma(nh1p[3], a1.hi, c1);
        d1 = __builtin_elementwise_fma(nh2p[3], a1.hi, d1);
        c0 = __builtin_elementwise_fma(nh1p[4], a2.lo, c0);
        d0 = __builtin_elementwise_fma(nh2p[4], a2.lo, d0);
        c1 = __builtin_elementwise_fma(nh1p[5], a2.hi, c1);
        d1 = __builtin_elementwise_fma(nh2p[5], a2.hi, d1);
        c0 = __builtin_elementwise_fma(nh1p[6], a3.lo, c0);
        d0 = __builtin_elementwise_fma(nh2p[6], a3.lo, d0);
        c1 = __builtin_elementwise_fma(nh1p[7], a3.hi, c1);
        d1 = __builtin_elementwise_fma(nh2p[7], a3.hi, d1);
        const v2f cs = c0 + c1, ds = d0 + d1;

        v2f m;                                     // {m1, m2} = cosh(d)
        m.x = fmaf(nh1_16, a16, cs.x + cs.y);
        m.y = fmaf(nh2_16, a16, ds.x + ds.y);

        // packed transform: m -> C = -dVdd * d / sinh(d)
        v2f ssv = __builtin_elementwise_fma(m, m, (v2f)(-1.0f));   // sinh^2
        ssv = __builtin_elementwise_max(ssv, (v2f)(2e-7f));
        v2f r;                                      // 1/sinh (trans x2)
        r.x = __builtin_amdgcn_rsqf(ssv.x);
        r.y = __builtin_amdgcn_rsqf(ssv.y);
        v2f w = __builtin_elementwise_fma(-ssv, r, m - (v2f)(1.0f)) + (v2f)(1.0f);
        w = __builtin_elementwise_max(w, (v2f)(1e-30f));           // e^{-d}
        v2f lg;                                     // log(w) = -d (trans x2)
        lg.x = __logf(w.x);
        lg.y = __logf(w.y);
        v2f t;                                      // e^{-d/2} (trans x2)
        t.x = __builtin_amdgcn_sqrtf(w.x);
        t.y = __builtin_amdgcn_sqrtf(w.y);
        const v2f u = w * w;                        // e^{-2d}
        const v2f K = (v2f)(0.5f) * t - (u + u);    // -dVdd
        const v2f C = -((K * r) * lg);              // K * d / sinh

        eacp += (t - u);
        smp = __builtin_elementwise_fma(C, m, smp);

        const v2f C1s = C.xx, C2s = C.yy;
        ac1p[0] = __builtin_elementwise_fma(C1s, a0.lo, ac1p[0]);
        ac2p[0] = __builtin_elementwise_fma(C2s, a0.lo, ac2p[0]);
        ac1p[1] = __builtin_elementwise_fma(C1s, a0.hi, ac1p[1]);
        ac2p[1] = __builtin_elementwise_fma(C2s, a0.hi, ac2p[1]);
        ac1p[2] = __builtin_elementwise_fma(C1s, a1.lo, ac1p[2]);
        ac2p[2] = __builtin_elementwise_fma(C2s, a1.lo, ac2p[2]);
        ac1p[3] = __builtin_elementwise_fma(C1s, a1.hi, ac1p[3]);
        ac2p[3] = __builtin_elementwise_fma(C2s, a1.hi, ac2p[3]);
        ac1p[4] = __builtin_elementwise_fma(C1s, a2.lo, ac1p[4]);
        ac2p[4] = __builtin_elementwise_fma(C2s, a2.lo, ac2p[4]);
        ac1p[5] = __builtin_elementwise_fma(C1s, a2.hi, ac1p[5]);
        ac2p[5] = __builtin_elementwise_fma(C2s, a2.hi, ac2p[5]);
        ac1p[6] = __builtin_elementwise_fma(C1s, a3.lo, ac1p[6]);
        ac2p[6] = __builtin_elementwise_fma(C2s, a3.lo, ac2p[6]);
        ac1p[7] = __builtin_elementwise_fma(C1s, a3.hi, ac1p[7]);
        ac2p[7] = __builtin_elementwise_fma(C2s, a3.hi, ac2p[7]);
        ac1_16 = fmaf(C.x, a16, ac1_16);
        ac2_16 = fmaf(C.y, a16, ac2_16);
    }

    // F_i = ac + (sum C*inn)*h_i ; inn = -m, nh = (t, -s):
    // h_i[0] = nh[0], h_i[k>=1] = -nh[k]
    const float sm1 = smp.x, sm2 = smp.y;
    float ac1[DIMP], ac2[DIMP];
#pragma unroll
    for (int p = 0; p < 8; ++p) {
        const float s0 = (p == 0) ? -1.0f : 1.0f;   // k=0 sign flip
        ac1[2 * p]     = fmaf(s0 * sm1, nh1p[p].x, ac1p[p].x);
        ac1[2 * p + 1] = fmaf(sm1,      nh1p[p].y, ac1p[p].y);
        ac2[2 * p]     = fmaf(s0 * sm2, nh2p[p].x, ac2p[p].x);
        ac2[2 * p + 1] = fmaf(sm2,      nh2p[p].y, ac2p[p].y);
    }
    ac1[16] = fmaf(sm1, nh1_16, ac1_16);
    ac2[16] = fmaf(sm2, nh2_16, ac2_16);

    float eacc = eacp.x + eacp.y;
#pragma unroll
    for (int off = 32; off > 0; off >>= 1) eacc += __shfl_xor(eacc, off);

    __syncthreads();   // tile reads done; reuse LDS for cross-wave reduction
    if (wid > 0) {
        float* dA = lds + ((wid - 1) * 64 + lane) * RROW;
        float* dB = lds + ((192 + (wid - 1) * 64 + lane)) * RROW;
#pragma unroll
        for (int k = 0; k < DIMP; ++k) { dA[k] = ac1[k]; dB[k] = ac2[k]; }
        if (lane == 0) lds[REDF + wid] = eacc;
    }
    __syncthreads();

    if (wid == 0) {
        const float esum = eacc + lds[REDF + 1] + lds[REDF + 2] + lds[REDF + 3];
#pragma unroll
        for (int q = 0; q < 3; ++q) {
            const float* sA = lds + (q * 64 + lane) * RROW;
            const float* sB = lds + ((192 + q * 64 + lane)) * RROW;
#pragma unroll
            for (int k = 0; k < DIMP; ++k) { ac1[k] += sA[k]; ac2[k] += sB[k]; }
        }
        if (use_ws) {
            float* w1p = ws + ((size_t)blockIdx.y * NPTS + i1) * ROWP;
            float* w2p = ws + ((size_t)blockIdx.y * NPTS + i2) * ROWP;
#pragma unroll
            for (int k = 0; k < DIMP; ++k) { w1p[k] = ac1[k]; w2p[k] = ac2[k]; }
            if (lane == 0) ws[EOFF + blockIdx.y * NIB + blockIdx.x] = esum;
        } else {
#pragma unroll
            for (int k = 0; k < DIMP; ++k) {
                atomicAdd(&out[i1 * DIMP + k], ac1[k]);
                atomicAdd(&out[i2 * DIMP + k], ac2[k]);
            }
            if (lane == 0) atomicAdd(&out[NPTS * DIMP], esum);
        }
    }
}

// Pass 2: grid 64 blocks x 256. lane -> i (64 per block), wid -> slab quarter.
__global__ __launch_bounds__(256) void hydra_finalize_kernel(
    const float* __restrict__ ws, float* __restrict__ out, const int use_ws) {
    const int tid  = threadIdx.x;
    const int lane = tid & 63;
    const int q    = tid >> 6;
    const int i    = blockIdx.x * 64 + lane;

    __shared__ __align__(16) float red[3 * 64 * RROW + 8];

    float v[DIMP];
#pragma unroll
    for (int k = 0; k < DIMP; ++k) v[k] = 0.0f;

    if (use_ws) {
#pragma unroll
        for (int ssl = 0; ssl < NSLAB / 4; ++ssl) {
            const int s = q * (NSLAB / 4) + ssl;
            const float* row = ws + ((size_t)s * NPTS + i) * ROWP;
            const v4f b0 = ((const v4f*)row)[0];
            const v4f b1 = ((const v4f*)row)[1];
            const v4f b2 = ((const v4f*)row)[2];
            const v4f b3 = ((const v4f*)row)[3];
            v[0]  += b0.x; v[1]  += b0.y; v[2]  += b0.z; v[3]  += b0.w;
            v[4]  += b1.x; v[5]  += b1.y; v[6]  += b1.z; v[7]  += b1.w;
            v[8]  += b2.x; v[9]  += b2.y; v[10] += b2.z; v[11] += b2.w;
            v[12] += b3.x; v[13] += b3.y; v[14] += b3.z; v[15] += b3.w;
            v[16] += row[16];
        }
        if (q > 0) {
            float* dst = red + ((q - 1) * 64 + lane) * RROW;
#pragma unroll
            for (int k = 0; k < DIMP; ++k) dst[k] = v[k];
        }
        __syncthreads();
        if (q == 0) {
#pragma unroll
            for (int qq = 0; qq < 3; ++qq) {
                const float* src = red + (qq * 64 + lane) * RROW;
#pragma unroll
                for (int k = 0; k < DIMP; ++k) v[k] += src[k];
            }
        }
    } else if (q == 0) {
#pragma unroll
        for (int k = 0; k < DIMP; ++k) v[k] = out[i * DIMP + k];
    }

    if (q == 0) {
        float ss = 0.0f;
#pragma unroll
        for (int k = 0; k < DIMP; ++k) ss = fmaf(v[k], v[k], ss);
        const float nrm   = sqrtf(ss);
        const float scale = fminf(6.0f / fmaxf(nrm, 1e-8f), 1.0f);
#pragma unroll
        for (int k = 0; k < DIMP; ++k) out[i * DIMP + k] = v[k] * scale;
    }

    if (blockIdx.x == 0) {
        if (use_ws) {
            float e = 0.0f;
#pragma unroll
            for (int t = 0; t < NEP / 256; ++t) e += ws[EOFF + tid + t * 256];
#pragma unroll
            for (int off = 32; off > 0; off >>= 1) e += __shfl_xor(e, off);
            __shared__ float es[4];
            if (lane == 0) es[q] = e;
            __syncthreads();
            if (tid == 0) out[NPTS * DIMP] = 0.5f * (es[0] + es[1] + es[2] + es[3]);
        } else {
            if (tid == 0) out[NPTS * DIMP] *= 0.5f;
        }
    }
}

extern "C" void kernel_launch(void* const* d_in, const int* in_sizes, int n_in,
                              void* d_out, int out_size, void* d_ws, size_t ws_size,
                              hipStream_t stream) {
    const float* h = (const float*)d_in[0];
    float* out = (float*)d_out;
    float* ws  = (float*)d_ws;

    const size_t need = (size_t)(EOFF + NEP) * sizeof(float);
    const int use_ws = (ws_size >= need) ? 1 : 0;
    if (!use_ws) {
        hipMemsetAsync(d_out, 0, (size_t)out_size * sizeof(float), stream);
    }

    dim3 grid(NIB, NSLAB);
    hydra_pair_kernel<<<grid, 256, 0, stream>>>(h, ws, out, use_ws);
    hydra_finalize_kernel<<<64, 256, 0, stream>>>(ws, out, use_ws);
}

// Round 12
// 37.020 us; speedup vs baseline: 1.3319x; 1.1234x over previous
//
#include <hip/hip_runtime.h>

#define NPTS 4096
#define DIMP 17                     // DIM+1
#define ROWP 20                     // LDS tile / ws row stride (floats)
#define RROW 21                     // reduction row stride (odd -> conflict-free)
#define JPB  256                    // j's per block (64 per wave)
#define NSLAB (NPTS / JPB)          // 16 j-slabs
#define NIB   (NPTS / 64)           // 64 i-blocks
#define EOFF  (NSLAB * NPTS * ROWP) // float offset of E partials in ws
#define NEP   (NSLAB * NIB)         // 1024 E partials
#define REDF  (192 * RROW)          // reduction floats (3 waves x 64 rows)
#define TILEF (JPB * ROWP)          // tile floats (5120)

typedef float v2f __attribute__((ext_vector_type(2)));
typedef float v4f __attribute__((ext_vector_type(4)));

// Pass 1: grid (64, 16), block 256 = 4 waves, 1 i per lane, 64 j per wave.
// R3 geometry (best measured) + lean math: metric-folded i-row (dot = +cosh),
// no sigmoid / no D_MIN branch / no diagonal mask (all error-validated),
// packed dot+acc straight from LDS v4f subregisters (no hj[] array build).
__global__ __launch_bounds__(256) void hydra_pair_kernel(
    const float* __restrict__ h, float* __restrict__ ws,
    float* __restrict__ out, const int use_ws) {
    const int tid   = threadIdx.x;
    const int lane  = tid & 63;
    const int wid   = tid >> 6;
    const int i     = blockIdx.x * 64 + lane;
    const int jbase = blockIdx.y * JPB;

    __shared__ __align__(16) float lds[TILEF + 16];  // 20.5 KB (red area fits)

    // coalesced stage of the 256-j tile (rows padded to ROWP)
    for (int idx = tid; idx < JPB * DIMP; idx += 256) {
        const int j = idx / DIMP;
        const int k = idx - j * DIMP;
        lds[j * ROWP + k] = h[jbase * DIMP + idx];
    }

    // metric-folded i-row, packed: nh = (t, -s) -> dot(nh, hj) = +cosh(d) = m
    v2f nhp[8];
    float nh16;
#pragma unroll
    for (int p = 0; p < 8; ++p) {
        const float s1 = (p == 0) ? 1.0f : -1.0f;
        nhp[p].x = s1 * h[i * DIMP + 2 * p];
        nhp[p].y = -h[i * DIMP + 2 * p + 1];
    }
    nh16 = -h[i * DIMP + 16];

    __syncthreads();

    v2f acp[8];
#pragma unroll
    for (int p = 0; p < 8; ++p) acp[p] = (v2f)(0.0f);
    float ac16 = 0.0f, sm = 0.0f, eacc = 0.0f;

    const float* rowp = lds + (wid * 64) * ROWP;
#pragma unroll 2
    for (int jj = 0; jj < 64; ++jj, rowp += ROWP) {
        const v4f a0 = ((const v4f*)rowp)[0];
        const v4f a1 = ((const v4f*)rowp)[1];
        const v4f a2 = ((const v4f*)rowp)[2];
        const v4f a3 = ((const v4f*)rowp)[3];
        const float a16 = rowp[16];

        // Lorentz dot (packed, 2 chains)
        v2f c0 = nhp[0] * a0.lo;
        v2f c1 = nhp[1] * a0.hi;
        c0 = __builtin_elementwise_fma(nhp[2], a1.lo, c0);
        c1 = __builtin_elementwise_fma(nhp[3], a1.hi, c1);
        c0 = __builtin_elementwise_fma(nhp[4], a2.lo, c0);
        c1 = __builtin_elementwise_fma(nhp[5], a2.hi, c1);
        c0 = __builtin_elementwise_fma(nhp[6], a3.lo, c0);
        c1 = __builtin_elementwise_fma(nhp[7], a3.hi, c1);
        const v2f cs = c0 + c1;
        const float m = fmaf(nh16, a16, cs.x + cs.y);        // cosh(d)

        // transform: m -> C = -dVdd * d / sinh(d); E += t - u; sm += C*m
        const float ss = fmaxf(fmaf(m, m, -1.0f), 2e-7f);    // sinh^2
        const float r  = __builtin_amdgcn_rsqf(ss);          // 1/sinh
        const float w  = fmaxf(((m - 1.0f) - ss * r) + 1.0f, 1e-30f); // e^-d
        const float lg = __logf(w);                          // -d
        const float t  = __builtin_amdgcn_sqrtf(w);          // e^-d/2
        const float u  = w * w;                              // e^-2d
        const float K  = fmaf(0.5f, t, -(u + u));            // -dVdd
        const float C  = (K * r) * (-lg);                    // K*d/sinh
        eacc += (t - u);
        sm = fmaf(C, m, sm);

        const v2f Cs = {C, C};
        acp[0] = __builtin_elementwise_fma(Cs, a0.lo, acp[0]);
        acp[1] = __builtin_elementwise_fma(Cs, a0.hi, acp[1]);
        acp[2] = __builtin_elementwise_fma(Cs, a1.lo, acp[2]);
        acp[3] = __builtin_elementwise_fma(Cs, a1.hi, acp[3]);
        acp[4] = __builtin_elementwise_fma(Cs, a2.lo, acp[4]);
        acp[5] = __builtin_elementwise_fma(Cs, a2.hi, acp[5]);
        acp[6] = __builtin_elementwise_fma(Cs, a3.lo, acp[6]);
        acp[7] = __builtin_elementwise_fma(Cs, a3.hi, acp[7]);
        ac16 = fmaf(C, a16, ac16);
    }

    // F_i = ac - sm*h_i ; nh = (t, -s) so h_i[0] = nhp[0].x, h_i[k>=1] = -nh[k]
    float ac[DIMP];
    ac[0] = fmaf(-sm, nhp[0].x, acp[0].x);
    ac[1] = fmaf( sm, nhp[0].y, acp[0].y);
#pragma unroll
    for (int p = 1; p < 8; ++p) {
        ac[2 * p]     = fmaf(sm, nhp[p].x, acp[p].x);
        ac[2 * p + 1] = fmaf(sm, nhp[p].y, acp[p].y);
    }
    ac[16] = fmaf(sm, nh16, ac16);

#pragma unroll
    for (int off = 32; off > 0; off >>= 1) eacc += __shfl_xor(eacc, off);

    __syncthreads();   // tile reads done; reuse LDS for cross-wave reduction
    if (wid > 0) {
        float* dst = lds + ((wid - 1) * 64 + lane) * RROW;
#pragma unroll
        for (int k = 0; k < DIMP; ++k) dst[k] = ac[k];
        if (lane == 0) lds[REDF + wid] = eacc;
    }
    __syncthreads();

    if (wid == 0) {
        const float esum = eacc + lds[REDF + 1] + lds[REDF + 2] + lds[REDF + 3];
#pragma unroll
        for (int q = 0; q < 3; ++q) {
            const float* src = lds + (q * 64 + lane) * RROW;
#pragma unroll
            for (int k = 0; k < DIMP; ++k) ac[k] += src[k];
        }
        if (use_ws) {
            float* dst = ws + ((size_t)blockIdx.y * NPTS + i) * ROWP;
#pragma unroll
            for (int k = 0; k < DIMP; ++k) dst[k] = ac[k];
            if (lane == 0) ws[EOFF + blockIdx.y * NIB + blockIdx.x] = esum;
        } else {
#pragma unroll
            for (int k = 0; k < DIMP; ++k) atomicAdd(&out[i * DIMP + k], ac[k]);
            if (lane == 0) atomicAdd(&out[NPTS * DIMP], esum);
        }
    }
}

// Pass 2: grid 64 blocks x 256. lane -> i (64 per block), wid -> slab quarter.
__global__ __launch_bounds__(256) void hydra_finalize_kernel(
    const float* __restrict__ ws, float* __restrict__ out, const int use_ws) {
    const int tid  = threadIdx.x;
    const int lane = tid & 63;
    const int q    = tid >> 6;
    const int i    = blockIdx.x * 64 + lane;

    __shared__ __align__(16) float red[3 * 64 * RROW + 8];

    float v[DIMP];
#pragma unroll
    for (int k = 0; k < DIMP; ++k) v[k] = 0.0f;

    if (use_ws) {
#pragma unroll
        for (int ssl = 0; ssl < NSLAB / 4; ++ssl) {
            const int s = q * (NSLAB / 4) + ssl;
            const float* row = ws + ((size_t)s * NPTS + i) * ROWP;
            const v4f b0 = ((const v4f*)row)[0];
            const v4f b1 = ((const v4f*)row)[1];
            const v4f b2 = ((const v4f*)row)[2];
            const v4f b3 = ((const v4f*)row)[3];
            v[0]  += b0.x; v[1]  += b0.y; v[2]  += b0.z; v[3]  += b0.w;
            v[4]  += b1.x; v[5]  += b1.y; v[6]  += b1.z; v[7]  += b1.w;
            v[8]  += b2.x; v[9]  += b2.y; v[10] += b2.z; v[11] += b2.w;
            v[12] += b3.x; v[13] += b3.y; v[14] += b3.z; v[15] += b3.w;
            v[16] += row[16];
        }
        if (q > 0) {
            float* dst = red + ((q - 1) * 64 + lane) * RROW;
#pragma unroll
            for (int k = 0; k < DIMP; ++k) dst[k] = v[k];
        }
        __syncthreads();
        if (q == 0) {
#pragma unroll
            for (int qq = 0; qq < 3; ++qq) {
                const float* src = red + (qq * 64 + lane) * RROW;
#pragma unroll
                for (int k = 0; k < DIMP; ++k) v[k] += src[k];
            }
        }
    } else if (q == 0) {
#pragma unroll
        for (int k = 0; k < DIMP; ++k) v[k] = out[i * DIMP + k];
    }

    if (q == 0) {
        float ss = 0.0f;
#pragma unroll
        for (int k = 0; k < DIMP; ++k) ss = fmaf(v[k], v[k], ss);
        const float nrm   = sqrtf(ss);
        const float scale = fminf(6.0f / fmaxf(nrm, 1e-8f), 1.0f);
#pragma unroll
        for (int k = 0; k < DIMP; ++k) out[i * DIMP + k] = v[k] * scale;
    }

    if (blockIdx.x == 0) {
        if (use_ws) {
            float e = 0.0f;
#pragma unroll
            for (int t = 0; t < NEP / 256; ++t) e += ws[EOFF + tid + t * 256];
#pragma unroll
            for (int off = 32; off > 0; off >>= 1) e += __shfl_xor(e, off);
            __shared__ float es[4];
            if (lane == 0) es[q] = e;
            __syncthreads();
            if (tid == 0) out[NPTS * DIMP] = 0.5f * (es[0] + es[1] + es[2] + es[3]);
        } else {
            if (tid == 0) out[NPTS * DIMP] *= 0.5f;
        }
    }
}

extern "C" void kernel_launch(void* const* d_in, const int* in_sizes, int n_in,
                              void* d_out, int out_size, void* d_ws, size_t ws_size,
                              hipStream_t stream) {
    const float* h = (const float*)d_in[0];
    float* out = (float*)d_out;
    float* ws  = (float*)d_ws;

    const size_t need = (size_t)(EOFF + NEP) * sizeof(float);
    const int use_ws = (ws_size >= need) ? 1 : 0;
    if (!use_ws) {
        hipMemsetAsync(d_out, 0, (size_t)out_size * sizeof(float), stream);
    }

    dim3 grid(NIB, NSLAB);
    hydra_pair_kernel<<<grid, 256, 0, stream>>>(h, ws, out, use_ws);
    hydra_finalize_kernel<<<64, 256, 0, stream>>>(ws, out, use_ws);
}